// Round 9
// baseline (350.259 us; speedup 1.0000x reference)
//
#include <hip/hip_runtime.h>
#include <hip/hip_fp16.h>

#define N_NODES 100000
#define N_EDGES 1600000
#define E_TOT   (N_EDGES + N_NODES)
#define NEG_SLOPE 0.2f

#define BSH   9
#define BSZ   512                         // nodes per bucket
#define NBKT  ((N_NODES + BSZ - 1) / BSZ) // 196
#define CAP   10240                       // padded bucket capacity (mean 8673)
#define EPB   8192                        // edges per partition block
#define PART_B ((E_TOT + EPB - 1) / EPB)  // 208

__device__ __forceinline__ float lrelu(float v) { return v > 0.f ? v : NEG_SLOPE * v; }

__device__ __forceinline__ float f16lo(unsigned u) {
    return __half2float(__ushort_as_half((unsigned short)(u & 0xFFFFu)));
}
__device__ __forceinline__ float f16hi(unsigned u) {
    return __half2float(__ushort_as_half((unsigned short)(u >> 16)));
}

// ---- init bucket cursors to static padded bases ----
__global__ __launch_bounds__(256) void k_init(int* __restrict__ gcur) {
    int t = threadIdx.x;
    if (t < NBKT) gcur[t] = t * CAP;
}

// ---- partition edges into padded buckets ----
// packed = (dst & 511) << 17 | src   (src < 2^17)
__global__ __launch_bounds__(256) void k_part(const int* __restrict__ ei,
                                              int* __restrict__ gcur,
                                              int* __restrict__ packed) {
    __shared__ int lcnt[NBKT];
    __shared__ int gpos[NBKT];
    __shared__ int lcur[NBKT];
    int t = threadIdx.x;
    for (int i = t; i < NBKT; i += 256) lcnt[i] = 0;
    __syncthreads();
    size_t base = (size_t)blockIdx.x * EPB;
    for (int i = t; i < EPB; i += 256) {
        size_t e = base + i;
        if (e < E_TOT) {
            int d = (e < N_EDGES) ? ei[N_EDGES + e] : (int)(e - N_EDGES);
            atomicAdd(&lcnt[d >> BSH], 1);
        }
    }
    __syncthreads();
    for (int i = t; i < NBKT; i += 256) {
        int c = lcnt[i];
        gpos[i] = c ? atomicAdd(&gcur[i], c) : 0;
        lcur[i] = 0;
    }
    __syncthreads();
    for (int i = t; i < EPB; i += 256) {
        size_t e = base + i;
        if (e < E_TOT) {
            int s, d;
            if (e < N_EDGES) { s = ei[e]; d = ei[N_EDGES + e]; }
            else             { s = (int)(e - N_EDGES); d = s; }
            int b = d >> BSH;
            int c = atomicAdd(&lcur[b], 1);
            packed[gpos[b] + c] = ((d & (BSZ - 1)) << 17) | s;
        }
    }
}

// ---- per-bucket: count from cursor, local scan -> rowptr+deg, col scatter ----
__global__ __launch_bounds__(512) void k_build(const int* __restrict__ packed,
                                               const int* __restrict__ gcur,
                                               int* __restrict__ rowptr,
                                               int* __restrict__ deg,
                                               int* __restrict__ col) {
    int t = threadIdx.x;
    int b = blockIdx.x;
    int nb = b << BSH;
    int ebeg = b * CAP;
    int eend = gcur[b];
    __shared__ int cnt[BSZ];
    __shared__ int ps[BSZ];
    cnt[t] = 0;
    __syncthreads();
    for (int i = ebeg + t; i < eend; i += 512)
        atomicAdd(&cnt[packed[i] >> 17], 1);
    __syncthreads();
    int v = cnt[t];
    ps[t] = v;
    __syncthreads();
    for (int off = 1; off < 512; off <<= 1) {
        int u = (t >= off) ? ps[t - off] : 0;
        __syncthreads();
        ps[t] += u;
        __syncthreads();
    }
    int myofs = ebeg + ps[t] - v;   // padded-global col offset of node nb+t
    int n = nb + t;
    if (n < N_NODES) { rowptr[n] = myofs; deg[n] = v; }
    __syncthreads();
    cnt[t] = myofs;                  // reuse as global-position cursor
    __syncthreads();
    for (int i = ebeg + t; i < eend; i += 512) {
        int p = packed[i];
        int pos = atomicAdd(&cnt[p >> 17], 1);
        col[pos] = p & 0x1FFFF;
    }
}

// ---- Layer 1 GEMM: h1(fp16) = x @ W1, fused attention logits ----
__global__ __launch_bounds__(256) void k_gemm1(const float* __restrict__ x,
                                               const float* __restrict__ W1,
                                               const float* __restrict__ a_src,
                                               const float* __restrict__ a_dst,
                                               unsigned short* __restrict__ h1h,
                                               float* __restrict__ als,
                                               float* __restrict__ ald) {
    __shared__ float xs[64 * 128];  // 32 KB
    int t = threadIdx.x;
    int c = t & 31, rg = t >> 5;
    int nb = blockIdx.x * 64;
    const float4* xv4 = (const float4*)x;
    float4* xs4 = (float4*)xs;
    size_t base4 = (size_t)nb * 32;
    const size_t lim4 = (size_t)N_NODES * 32;
#pragma unroll
    for (int i = 0; i < 8; ++i) {
        size_t g = base4 + t + i * 256;
        if (g < lim4) xs4[t + i * 256] = xv4[g];
    }
    __syncthreads();
    const float4* W1v = (const float4*)W1;
    float4 acc[8];
#pragma unroll
    for (int i = 0; i < 8; ++i) acc[i] = make_float4(0.f, 0.f, 0.f, 0.f);
#pragma unroll 4
    for (int k = 0; k < 128; ++k) {
        float4 w = W1v[k * 32 + c];
#pragma unroll
        for (int i = 0; i < 8; ++i) {
            float xv = xs[(rg + 8 * i) * 128 + k];
            acc[i].x = fmaf(xv, w.x, acc[i].x);
            acc[i].y = fmaf(xv, w.y, acc[i].y);
            acc[i].z = fmaf(xv, w.z, acc[i].z);
            acc[i].w = fmaf(xv, w.w, acc[i].w);
        }
    }
    float4 as4 = ((const float4*)a_src)[c];
    float4 ad4 = ((const float4*)a_dst)[c];
#pragma unroll
    for (int i = 0; i < 8; ++i) {
        int n = nb + rg + 8 * i;
        if (n < N_NODES) {
            ushort4 hb;
            hb.x = __half_as_ushort(__float2half(acc[i].x));
            hb.y = __half_as_ushort(__float2half(acc[i].y));
            hb.z = __half_as_ushort(__float2half(acc[i].z));
            hb.w = __half_as_ushort(__float2half(acc[i].w));
            ((ushort4*)h1h)[(size_t)n * 32 + c] = hb;
        }
        float vs = acc[i].x * as4.x + acc[i].y * as4.y + acc[i].z * as4.z + acc[i].w * as4.w;
        float vd = acc[i].x * ad4.x + acc[i].y * ad4.y + acc[i].z * ad4.z + acc[i].w * ad4.w;
        vs += __shfl_down(vs, 4, 8); vs += __shfl_down(vs, 2, 8); vs += __shfl_down(vs, 1, 8);
        vd += __shfl_down(vd, 4, 8); vd += __shfl_down(vd, 2, 8); vd += __shfl_down(vd, 1, 8);
        if ((c & 7) == 0 && n < N_NODES) {
            int h = c >> 3;
            als[n * 4 + h] = vs;
            ald[n * 4 + h] = vd;
        }
    }
}

// ---- Fused layer-1 aggregation + layer-2 GEMM (out1 never materialized) ----
// Wave per node. Gather phase as R8 (4 edges/iter uint4 row gathers).
// Epilogue: all lanes hold full out1 row (8ch/lane); slot0 lanes write relu'd
// row to per-wave LDS; 16 lanes compute h2[c] = sum_k row[k]*W2s[k*16+c]
// (row read = broadcast, W2s read = conflict-free), then als2/ald2 + h2h(fp16).
__global__ __launch_bounds__(256) void k_agg1(const unsigned short* __restrict__ h1h,
                                              const float* __restrict__ als,
                                              const float* __restrict__ ald,
                                              const int* __restrict__ rowptr,
                                              const int* __restrict__ deg,
                                              const int* __restrict__ col,
                                              const float* __restrict__ b1,
                                              const float* __restrict__ W2,
                                              const float* __restrict__ as2,
                                              const float* __restrict__ ad2,
                                              unsigned short* __restrict__ h2h,
                                              float* __restrict__ als2,
                                              float* __restrict__ ald2) {
    __shared__ float W2s[128 * 16];        // 8 KB
    __shared__ float sex_all[4][64 * 4];   // 4 KB per-wave ex[q][head]
    __shared__ int   scol_all[4][64];      // 1 KB per-wave col cache
    __shared__ float row_all[4][128];      // 2 KB per-wave out1 row
    int t = threadIdx.x;
    for (int i = t; i < 2048; i += 256) W2s[i] = W2[i];
    __syncthreads();   // only block-wide barrier; waves independent after

    int w = t >> 6;
    int lane = t & 63;
    int n = blockIdx.x * 4 + w;
    int slot = lane >> 4, cg = lane & 15;
    int hd = cg >> 2;
    float* sex = sex_all[w];
    int* scol = scol_all[w];
    float* row = row_all[w];
    float4 ald4 = ((const float4*)ald)[n];
    int beg = rowptr[n], dtot = deg[n];
    float a0 = 0.f, a1 = 0.f, a2 = 0.f, a3 = 0.f;
    float a4 = 0.f, a5 = 0.f, a6 = 0.f, a7 = 0.f, den = 0.f;
    const float4* als4p = (const float4*)als;
    for (int base = 0; base < dtot; base += 64) {
        int cnt = min(64, dtot - base);
        int myc = 0;
        if (lane < cnt) myc = col[beg + base + lane];
        // WAR: previous chunk's ds_reads must drain before overwriting LDS
        __asm__ volatile("s_waitcnt lgkmcnt(0)" ::: "memory");
        if (lane < cnt) {
            scol[lane] = myc;
            float4 as4 = als4p[myc];
            float4 e4;
            e4.x = __expf(lrelu(as4.x + ald4.x));
            e4.y = __expf(lrelu(as4.y + ald4.y));
            e4.z = __expf(lrelu(as4.z + ald4.z));
            e4.w = __expf(lrelu(as4.w + ald4.w));
            ((float4*)sex)[lane] = e4;
        }
        __asm__ volatile("s_waitcnt lgkmcnt(0)" ::: "memory");
#pragma unroll 2
        for (int q4 = 0; q4 < cnt; q4 += 4) {
            int myq = q4 + slot;
            int cq = min(myq, cnt - 1);
            int s = scol[cq];
            float ex = (myq < cnt) ? sex[cq * 4 + hd] : 0.f;
            uint4 hv = *(const uint4*)((const char*)h1h + (((size_t)s << 8) + (cg << 4)));
            a0 = fmaf(ex, f16lo(hv.x), a0);
            a1 = fmaf(ex, f16hi(hv.x), a1);
            a2 = fmaf(ex, f16lo(hv.y), a2);
            a3 = fmaf(ex, f16hi(hv.y), a3);
            a4 = fmaf(ex, f16lo(hv.z), a4);
            a5 = fmaf(ex, f16hi(hv.z), a5);
            a6 = fmaf(ex, f16lo(hv.w), a6);
            a7 = fmaf(ex, f16hi(hv.w), a7);
            den += ex;
        }
    }
    a0 += __shfl_xor(a0, 16, 64); a1 += __shfl_xor(a1, 16, 64);
    a2 += __shfl_xor(a2, 16, 64); a3 += __shfl_xor(a3, 16, 64);
    a4 += __shfl_xor(a4, 16, 64); a5 += __shfl_xor(a5, 16, 64);
    a6 += __shfl_xor(a6, 16, 64); a7 += __shfl_xor(a7, 16, 64);
    den += __shfl_xor(den, 16, 64);
    a0 += __shfl_xor(a0, 32, 64); a1 += __shfl_xor(a1, 32, 64);
    a2 += __shfl_xor(a2, 32, 64); a3 += __shfl_xor(a3, 32, 64);
    a4 += __shfl_xor(a4, 32, 64); a5 += __shfl_xor(a5, 32, 64);
    a6 += __shfl_xor(a6, 32, 64); a7 += __shfl_xor(a7, 32, 64);
    den += __shfl_xor(den, 32, 64);

    // ---- fused epilogue: relu(out1 row) -> LDS, then gemm2 on 16 lanes ----
    if (slot == 0) {
        float inv = 1.0f / den;
        float4 bA = ((const float4*)b1)[2 * cg];
        float4 bB = ((const float4*)b1)[2 * cg + 1];
        float4 rA, rB;
        rA.x = fmaxf(fmaf(a0, inv, bA.x), 0.f);
        rA.y = fmaxf(fmaf(a1, inv, bA.y), 0.f);
        rA.z = fmaxf(fmaf(a2, inv, bA.z), 0.f);
        rA.w = fmaxf(fmaf(a3, inv, bA.w), 0.f);
        rB.x = fmaxf(fmaf(a4, inv, bB.x), 0.f);
        rB.y = fmaxf(fmaf(a5, inv, bB.y), 0.f);
        rB.z = fmaxf(fmaf(a6, inv, bB.z), 0.f);
        rB.w = fmaxf(fmaf(a7, inv, bB.w), 0.f);
        ((float4*)row)[2 * cg]     = rA;
        ((float4*)row)[2 * cg + 1] = rB;
    }
    __asm__ volatile("s_waitcnt lgkmcnt(0)" ::: "memory");
    if (slot == 0) {
        float hsum = 0.f;
        const float2* row2 = (const float2*)row;
#pragma unroll 8
        for (int k2 = 0; k2 < 64; ++k2) {
            float2 r = row2[k2];               // broadcast read (same addr, 16 lanes)
            hsum = fmaf(r.x, W2s[(2 * k2) * 16 + cg], hsum);      // conflict-free
            hsum = fmaf(r.y, W2s[(2 * k2 + 1) * 16 + cg], hsum);
        }
        float vs = hsum * as2[cg];
        float vd = hsum * ad2[cg];
        vs += __shfl_xor(vs, 1, 64); vd += __shfl_xor(vd, 1, 64);
        vs += __shfl_xor(vs, 2, 64); vd += __shfl_xor(vd, 2, 64);
        vs += __shfl_xor(vs, 4, 64); vd += __shfl_xor(vd, 4, 64);
        vs += __shfl_xor(vs, 8, 64); vd += __shfl_xor(vd, 8, 64);
        h2h[(size_t)n * 16 + cg] = __half_as_ushort(__float2half(hsum));
        if (cg == 0) { als2[n] = vs; ald2[n] = vd; }
    }
}

// ---- Layer 2 aggregation: wave/node, 16 edges/iter, batched exp in LDS ----
__global__ __launch_bounds__(256) void k_agg2(const unsigned short* __restrict__ h2h,
                                              const float* __restrict__ als,
                                              const float* __restrict__ ald,
                                              const int* __restrict__ rowptr,
                                              const int* __restrict__ deg,
                                              const int* __restrict__ col,
                                              const float* __restrict__ b2,
                                              float* __restrict__ out) {
    __shared__ float sex_all[4][64];
    __shared__ int   scol_all[4][64];
    int w = threadIdx.x >> 6;
    int lane = threadIdx.x & 63;
    int n = blockIdx.x * 4 + w;
    int slot = lane >> 2, q = lane & 3;
    float* sex = sex_all[w];
    int* scol = scol_all[w];
    float ad = ald[n];
    int beg = rowptr[n], dtot = deg[n];
    float a0 = 0.f, a1 = 0.f, a2 = 0.f, a3 = 0.f, den = 0.f;
    for (int base = 0; base < dtot; base += 64) {
        int cnt = min(64, dtot - base);
        int myc = 0;
        if (lane < cnt) myc = col[beg + base + lane];
        __asm__ volatile("s_waitcnt lgkmcnt(0)" ::: "memory");
        if (lane < cnt) {
            scol[lane] = myc;
            sex[lane] = __expf(lrelu(als[myc] + ad));
        }
        __asm__ volatile("s_waitcnt lgkmcnt(0)" ::: "memory");
#pragma unroll 2
        for (int q16 = 0; q16 < cnt; q16 += 16) {
            int myq = q16 + slot;
            int cq = min(myq, cnt - 1);
            int s = scol[cq];
            float ex = (myq < cnt) ? sex[cq] : 0.f;
            uint2 hv = *(const uint2*)((const char*)h2h + ((size_t)s * 32u + (q << 3)));
            a0 = fmaf(ex, f16lo(hv.x), a0);
            a1 = fmaf(ex, f16hi(hv.x), a1);
            a2 = fmaf(ex, f16lo(hv.y), a2);
            a3 = fmaf(ex, f16hi(hv.y), a3);
            den += ex;
        }
    }
#pragma unroll
    for (int off = 4; off <= 32; off <<= 1) {
        a0 += __shfl_xor(a0, off, 64);
        a1 += __shfl_xor(a1, off, 64);
        a2 += __shfl_xor(a2, off, 64);
        a3 += __shfl_xor(a3, off, 64);
        den += __shfl_xor(den, off, 64);
    }
    if (slot == 0) {
        float inv = 1.0f / den;
        float4 b4 = ((const float4*)b2)[q];
        float4 o;
        o.x = fmaf(a0, inv, b4.x);
        o.y = fmaf(a1, inv, b4.y);
        o.z = fmaf(a2, inv, b4.z);
        o.w = fmaf(a3, inv, b4.w);
        ((float4*)out)[(size_t)n * 4 + q] = o;
    }
}

extern "C" void kernel_launch(void* const* d_in, const int* in_sizes, int n_in,
                              void* d_out, int out_size, void* d_ws, size_t ws_size,
                              hipStream_t stream) {
    const float* x   = (const float*)d_in[0];
    const int*   ei  = (const int*)d_in[1];
    const float* W1  = (const float*)d_in[2];
    const float* as1 = (const float*)d_in[3];
    const float* ad1 = (const float*)d_in[4];
    const float* b1  = (const float*)d_in[5];
    const float* W2  = (const float*)d_in[6];
    const float* as2 = (const float*)d_in[7];
    const float* ad2 = (const float*)d_in[8];
    const float* b2  = (const float*)d_in[9];
    float* out = (float*)d_out;

    char* ws = (char*)d_ws;
    size_t off = 0;
    auto alloc = [&](size_t bytes) -> void* {
        void* p = ws + off;
        off += (bytes + 255) & ~(size_t)255;
        return p;
    };
    unsigned short* h1h = (unsigned short*)alloc((size_t)N_NODES * 128 * 2);
    float* als1v = (float*)alloc((size_t)N_NODES * 4 * 4);
    float* ald1v = (float*)alloc((size_t)N_NODES * 4 * 4);
    unsigned short* h2h = (unsigned short*)alloc((size_t)N_NODES * 16 * 2);
    float* als2v = (float*)alloc((size_t)N_NODES * 4);
    float* ald2v = (float*)alloc((size_t)N_NODES * 4);
    int* rowptr  = (int*)alloc((size_t)N_NODES * 4);
    int* degv    = (int*)alloc((size_t)N_NODES * 4);
    int* gcur    = (int*)alloc((size_t)NBKT * 4);
    int* packed  = (int*)alloc((size_t)NBKT * CAP * 4);
    int* colA    = (int*)alloc((size_t)NBKT * CAP * 4);

    k_init<<<1, 256, 0, stream>>>(gcur);
    k_part<<<PART_B, 256, 0, stream>>>(ei, gcur, packed);
    k_build<<<NBKT, 512, 0, stream>>>(packed, gcur, rowptr, degv, colA);
    k_gemm1<<<(N_NODES + 63) / 64, 256, 0, stream>>>(x, W1, as1, ad1, h1h, als1v, ald1v);
    k_agg1<<<N_NODES / 4, 256, 0, stream>>>(h1h, als1v, ald1v, rowptr, degv, colA,
                                            b1, W2, as2, ad2, h2h, als2v, ald2v);
    k_agg2<<<N_NODES / 4, 256, 0, stream>>>(h2h, als2v, ald2v, rowptr, degv, colA, b2, out);
}

// Round 10
// 314.010 us; speedup vs baseline: 1.1154x; 1.1154x over previous
//
#include <hip/hip_runtime.h>
#include <hip/hip_fp16.h>

#define N_NODES 100000
#define N_EDGES 1600000
#define E_TOT   (N_EDGES + N_NODES)
#define NEG_SLOPE 0.2f

#define BSH   9
#define BSZ   512                         // nodes per bucket
#define NBKT  ((N_NODES + BSZ - 1) / BSZ) // 196
#define CAP   10240                       // padded bucket capacity (mean 8673)
#define EPB   4096                        // edges per partition block
#define PART_B ((E_TOT + EPB - 1) / EPB)  // 416
#define GEMM1_B ((N_NODES + 63) / 64)     // 1563

__device__ __forceinline__ float lrelu(float v) { return v > 0.f ? v : NEG_SLOPE * v; }

__device__ __forceinline__ float f16lo(unsigned u) {
    return __half2float(__ushort_as_half((unsigned short)(u & 0xFFFFu)));
}
__device__ __forceinline__ float f16hi(unsigned u) {
    return __half2float(__ushort_as_half((unsigned short)(u >> 16)));
}

// ---- Fused launch 1: edge partition (blocks [0,PART_B)) + layer-1 GEMM ----
// The two roles are data-independent; co-launching lets gemm1's 1563 blocks
// backfill CUs while part's 416 latency-bound blocks run.
__global__ __launch_bounds__(256) void k_part_gemm1(
        const int* __restrict__ ei, int* __restrict__ gcur, int* __restrict__ packed,
        const float* __restrict__ x, const float* __restrict__ W1,
        const float* __restrict__ a_src, const float* __restrict__ a_dst,
        unsigned short* __restrict__ h1h, float* __restrict__ als,
        float* __restrict__ ald) {
    __shared__ __align__(16) union {
        float xs[64 * 128];                       // 32 KB (gemm1 role)
        struct { int lcnt[NBKT]; int gpos[NBKT]; int lcur[NBKT]; } p;  // part role
    } sm;
    int t = threadIdx.x;
    if (blockIdx.x < PART_B) {
        // ---------------- partition role ----------------
        for (int i = t; i < NBKT; i += 256) sm.p.lcnt[i] = 0;
        __syncthreads();
        size_t base = (size_t)blockIdx.x * EPB;
        for (int i = t; i < EPB; i += 256) {
            size_t e = base + i;
            if (e < E_TOT) {
                int d = (e < N_EDGES) ? ei[N_EDGES + e] : (int)(e - N_EDGES);
                atomicAdd(&sm.p.lcnt[d >> BSH], 1);
            }
        }
        __syncthreads();
        for (int i = t; i < NBKT; i += 256) {
            int c = sm.p.lcnt[i];
            // relative cursor (gcur zero-initialized by memsetAsync)
            sm.p.gpos[i] = c ? (i * CAP + atomicAdd(&gcur[i], c)) : 0;
            sm.p.lcur[i] = 0;
        }
        __syncthreads();
        for (int i = t; i < EPB; i += 256) {
            size_t e = base + i;
            if (e < E_TOT) {
                int s, d;
                if (e < N_EDGES) { s = ei[e]; d = ei[N_EDGES + e]; }
                else             { s = (int)(e - N_EDGES); d = s; }
                int b = d >> BSH;
                int c = atomicAdd(&sm.p.lcur[b], 1);
                packed[sm.p.gpos[b] + c] = ((d & (BSZ - 1)) << 17) | s;
            }
        }
        return;
    }
    // ---------------- gemm1 role ----------------
    int c = t & 31, rg = t >> 5;
    int nb = (blockIdx.x - PART_B) * 64;
    const float4* xv4 = (const float4*)x;
    float4* xs4 = (float4*)sm.xs;
    size_t base4 = (size_t)nb * 32;
    const size_t lim4 = (size_t)N_NODES * 32;
#pragma unroll
    for (int i = 0; i < 8; ++i) {
        size_t g = base4 + t + i * 256;
        if (g < lim4) xs4[t + i * 256] = xv4[g];
    }
    __syncthreads();
    const float4* W1v = (const float4*)W1;
    float4 acc[8];
#pragma unroll
    for (int i = 0; i < 8; ++i) acc[i] = make_float4(0.f, 0.f, 0.f, 0.f);
#pragma unroll 4
    for (int k = 0; k < 128; ++k) {
        float4 w = W1v[k * 32 + c];
#pragma unroll
        for (int i = 0; i < 8; ++i) {
            float xv = sm.xs[(rg + 8 * i) * 128 + k];
            acc[i].x = fmaf(xv, w.x, acc[i].x);
            acc[i].y = fmaf(xv, w.y, acc[i].y);
            acc[i].z = fmaf(xv, w.z, acc[i].z);
            acc[i].w = fmaf(xv, w.w, acc[i].w);
        }
    }
    float4 as4 = ((const float4*)a_src)[c];
    float4 ad4 = ((const float4*)a_dst)[c];
#pragma unroll
    for (int i = 0; i < 8; ++i) {
        int n = nb + rg + 8 * i;
        if (n < N_NODES) {
            ushort4 hb;
            hb.x = __half_as_ushort(__float2half(acc[i].x));
            hb.y = __half_as_ushort(__float2half(acc[i].y));
            hb.z = __half_as_ushort(__float2half(acc[i].z));
            hb.w = __half_as_ushort(__float2half(acc[i].w));
            ((ushort4*)h1h)[(size_t)n * 32 + c] = hb;
        }
        float vs = acc[i].x * as4.x + acc[i].y * as4.y + acc[i].z * as4.z + acc[i].w * as4.w;
        float vd = acc[i].x * ad4.x + acc[i].y * ad4.y + acc[i].z * ad4.z + acc[i].w * ad4.w;
        vs += __shfl_down(vs, 4, 8); vs += __shfl_down(vs, 2, 8); vs += __shfl_down(vs, 1, 8);
        vd += __shfl_down(vd, 4, 8); vd += __shfl_down(vd, 2, 8); vd += __shfl_down(vd, 1, 8);
        if ((c & 7) == 0 && n < N_NODES) {
            int h = c >> 3;
            als[n * 4 + h] = vs;
            ald[n * 4 + h] = vd;
        }
    }
}

// ---- per-bucket: count from cursor, local scan -> rowptr+deg, col scatter ----
__global__ __launch_bounds__(512) void k_build(const int* __restrict__ packed,
                                               const int* __restrict__ gcur,
                                               int* __restrict__ rowptr,
                                               int* __restrict__ deg,
                                               int* __restrict__ col) {
    int t = threadIdx.x;
    int b = blockIdx.x;
    int nb = b << BSH;
    int ebeg = b * CAP;
    int eend = ebeg + gcur[b];     // relative cursor
    __shared__ int cnt[BSZ];
    __shared__ int ps[BSZ];
    cnt[t] = 0;
    __syncthreads();
    for (int i = ebeg + t; i < eend; i += 512)
        atomicAdd(&cnt[packed[i] >> 17], 1);
    __syncthreads();
    int v = cnt[t];
    ps[t] = v;
    __syncthreads();
    for (int off = 1; off < 512; off <<= 1) {
        int u = (t >= off) ? ps[t - off] : 0;
        __syncthreads();
        ps[t] += u;
        __syncthreads();
    }
    int myofs = ebeg + ps[t] - v;   // padded-global col offset of node nb+t
    int n = nb + t;
    if (n < N_NODES) { rowptr[n] = myofs; deg[n] = v; }
    __syncthreads();
    cnt[t] = myofs;                  // reuse as global-position cursor
    __syncthreads();
    for (int i = ebeg + t; i < eend; i += 512) {
        int p = packed[i];
        int pos = atomicAdd(&cnt[p >> 17], 1);
        col[pos] = p & 0x1FFFF;
    }
}

// ---- Layer 1 aggregation (R8 structure): wave/node, 4 edges/iter uint4 ----
__global__ __launch_bounds__(256) void k_agg1(const unsigned short* __restrict__ h1h,
                                              const float* __restrict__ als,
                                              const float* __restrict__ ald,
                                              const int* __restrict__ rowptr,
                                              const int* __restrict__ deg,
                                              const int* __restrict__ col,
                                              const float* __restrict__ b1,
                                              float* __restrict__ out1) {
    __shared__ float sex_all[4][64 * 4];   // per-wave ex[q][head]
    __shared__ int   scol_all[4][64];      // per-wave col cache
    int w = threadIdx.x >> 6;
    int lane = threadIdx.x & 63;
    int n = blockIdx.x * 4 + w;
    int slot = lane >> 4, cg = lane & 15;
    int hd = cg >> 2;
    float* sex = sex_all[w];
    int* scol = scol_all[w];
    float4 ald4 = ((const float4*)ald)[n];
    int beg = rowptr[n], dtot = deg[n];
    float a0 = 0.f, a1 = 0.f, a2 = 0.f, a3 = 0.f;
    float a4 = 0.f, a5 = 0.f, a6 = 0.f, a7 = 0.f, den = 0.f;
    const float4* als4p = (const float4*)als;
    for (int base = 0; base < dtot; base += 64) {
        int cnt = min(64, dtot - base);
        int myc = 0;
        if (lane < cnt) myc = col[beg + base + lane];
        // WAR: previous chunk's ds_reads must drain before overwriting LDS
        __asm__ volatile("s_waitcnt lgkmcnt(0)" ::: "memory");
        if (lane < cnt) {
            scol[lane] = myc;
            float4 as4 = als4p[myc];
            float4 e4;
            e4.x = __expf(lrelu(as4.x + ald4.x));
            e4.y = __expf(lrelu(as4.y + ald4.y));
            e4.z = __expf(lrelu(as4.z + ald4.z));
            e4.w = __expf(lrelu(as4.w + ald4.w));
            ((float4*)sex)[lane] = e4;
        }
        __asm__ volatile("s_waitcnt lgkmcnt(0)" ::: "memory");
#pragma unroll 2
        for (int q4 = 0; q4 < cnt; q4 += 4) {
            int myq = q4 + slot;
            int cq = min(myq, cnt - 1);
            int s = scol[cq];
            float ex = (myq < cnt) ? sex[cq * 4 + hd] : 0.f;
            uint4 hv = *(const uint4*)((const char*)h1h + (((size_t)s << 8) + (cg << 4)));
            a0 = fmaf(ex, f16lo(hv.x), a0);
            a1 = fmaf(ex, f16hi(hv.x), a1);
            a2 = fmaf(ex, f16lo(hv.y), a2);
            a3 = fmaf(ex, f16hi(hv.y), a3);
            a4 = fmaf(ex, f16lo(hv.z), a4);
            a5 = fmaf(ex, f16hi(hv.z), a5);
            a6 = fmaf(ex, f16lo(hv.w), a6);
            a7 = fmaf(ex, f16hi(hv.w), a7);
            den += ex;
        }
    }
    a0 += __shfl_xor(a0, 16, 64); a1 += __shfl_xor(a1, 16, 64);
    a2 += __shfl_xor(a2, 16, 64); a3 += __shfl_xor(a3, 16, 64);
    a4 += __shfl_xor(a4, 16, 64); a5 += __shfl_xor(a5, 16, 64);
    a6 += __shfl_xor(a6, 16, 64); a7 += __shfl_xor(a7, 16, 64);
    den += __shfl_xor(den, 16, 64);
    a0 += __shfl_xor(a0, 32, 64); a1 += __shfl_xor(a1, 32, 64);
    a2 += __shfl_xor(a2, 32, 64); a3 += __shfl_xor(a3, 32, 64);
    a4 += __shfl_xor(a4, 32, 64); a5 += __shfl_xor(a5, 32, 64);
    a6 += __shfl_xor(a6, 32, 64); a7 += __shfl_xor(a7, 32, 64);
    den += __shfl_xor(den, 32, 64);
    if (lane < 16) {
        float inv = 1.0f / den;
        float4 bA = ((const float4*)b1)[2 * lane];
        float4 bB = ((const float4*)b1)[2 * lane + 1];
        float4 oA, oB;
        oA.x = fmaxf(fmaf(a0, inv, bA.x), 0.f);
        oA.y = fmaxf(fmaf(a1, inv, bA.y), 0.f);
        oA.z = fmaxf(fmaf(a2, inv, bA.z), 0.f);
        oA.w = fmaxf(fmaf(a3, inv, bA.w), 0.f);
        oB.x = fmaxf(fmaf(a4, inv, bB.x), 0.f);
        oB.y = fmaxf(fmaf(a5, inv, bB.y), 0.f);
        oB.z = fmaxf(fmaf(a6, inv, bB.z), 0.f);
        oB.w = fmaxf(fmaf(a7, inv, bB.w), 0.f);
        ((float4*)out1)[(size_t)n * 32 + 2 * lane]     = oA;
        ((float4*)out1)[(size_t)n * 32 + 2 * lane + 1] = oB;
    }
}

// ---- Layer 2 GEMM: h2(fp16) = out1 @ W2, fused logits ----
__global__ __launch_bounds__(256) void k_gemm2(const float* __restrict__ out1,
                                               const float* __restrict__ W2,
                                               const float* __restrict__ a_src,
                                               const float* __restrict__ a_dst,
                                               unsigned short* __restrict__ h2h,
                                               float* __restrict__ als,
                                               float* __restrict__ ald) {
    __shared__ float W2s[128 * 16];
    __shared__ float xs[16 * 132];
    int t = threadIdx.x;
#pragma unroll
    for (int i = 0; i < 8; ++i) W2s[t + i * 256] = W2[t + i * 256];
    size_t base = (size_t)blockIdx.x * 16 * 128;
#pragma unroll
    for (int i = 0; i < 8; ++i) {
        int idx = t + i * 256;
        xs[(idx >> 7) * 132 + (idx & 127)] = out1[base + idx];
    }
    __syncthreads();
    int r = t >> 4, c = t & 15;
    float acc = 0.f;
    const float* xr = &xs[r * 132];
#pragma unroll 8
    for (int k = 0; k < 128; ++k) acc = fmaf(xr[k], W2s[k * 16 + c], acc);
    int n = blockIdx.x * 16 + r;
    h2h[(size_t)n * 16 + c] = __half_as_ushort(__float2half(acc));
    float vs = acc * a_src[c];
    float vd = acc * a_dst[c];
#pragma unroll
    for (int off = 8; off >= 1; off >>= 1) {
        vs += __shfl_down(vs, off, 16);
        vd += __shfl_down(vd, off, 16);
    }
    if (c == 0) { als[n] = vs; ald[n] = vd; }
}

// ---- Layer 2 aggregation: wave/node, 16 edges/iter, batched exp in LDS ----
__global__ __launch_bounds__(256) void k_agg2(const unsigned short* __restrict__ h2h,
                                              const float* __restrict__ als,
                                              const float* __restrict__ ald,
                                              const int* __restrict__ rowptr,
                                              const int* __restrict__ deg,
                                              const int* __restrict__ col,
                                              const float* __restrict__ b2,
                                              float* __restrict__ out) {
    __shared__ float sex_all[4][64];
    __shared__ int   scol_all[4][64];
    int w = threadIdx.x >> 6;
    int lane = threadIdx.x & 63;
    int n = blockIdx.x * 4 + w;
    int slot = lane >> 2, q = lane & 3;
    float* sex = sex_all[w];
    int* scol = scol_all[w];
    float ad = ald[n];
    int beg = rowptr[n], dtot = deg[n];
    float a0 = 0.f, a1 = 0.f, a2 = 0.f, a3 = 0.f, den = 0.f;
    for (int base = 0; base < dtot; base += 64) {
        int cnt = min(64, dtot - base);
        int myc = 0;
        if (lane < cnt) myc = col[beg + base + lane];
        __asm__ volatile("s_waitcnt lgkmcnt(0)" ::: "memory");
        if (lane < cnt) {
            scol[lane] = myc;
            sex[lane] = __expf(lrelu(als[myc] + ad));
        }
        __asm__ volatile("s_waitcnt lgkmcnt(0)" ::: "memory");
#pragma unroll 2
        for (int q16 = 0; q16 < cnt; q16 += 16) {
            int myq = q16 + slot;
            int cq = min(myq, cnt - 1);
            int s = scol[cq];
            float ex = (myq < cnt) ? sex[cq] : 0.f;
            uint2 hv = *(const uint2*)((const char*)h2h + ((size_t)s * 32u + (q << 3)));
            a0 = fmaf(ex, f16lo(hv.x), a0);
            a1 = fmaf(ex, f16hi(hv.x), a1);
            a2 = fmaf(ex, f16lo(hv.y), a2);
            a3 = fmaf(ex, f16hi(hv.y), a3);
            den += ex;
        }
    }
#pragma unroll
    for (int off = 4; off <= 32; off <<= 1) {
        a0 += __shfl_xor(a0, off, 64);
        a1 += __shfl_xor(a1, off, 64);
        a2 += __shfl_xor(a2, off, 64);
        a3 += __shfl_xor(a3, off, 64);
        den += __shfl_xor(den, off, 64);
    }
    if (slot == 0) {
        float inv = 1.0f / den;
        float4 b4 = ((const float4*)b2)[q];
        float4 o;
        o.x = fmaf(a0, inv, b4.x);
        o.y = fmaf(a1, inv, b4.y);
        o.z = fmaf(a2, inv, b4.z);
        o.w = fmaf(a3, inv, b4.w);
        ((float4*)out)[(size_t)n * 4 + q] = o;
    }
}

extern "C" void kernel_launch(void* const* d_in, const int* in_sizes, int n_in,
                              void* d_out, int out_size, void* d_ws, size_t ws_size,
                              hipStream_t stream) {
    const float* x   = (const float*)d_in[0];
    const int*   ei  = (const int*)d_in[1];
    const float* W1  = (const float*)d_in[2];
    const float* as1 = (const float*)d_in[3];
    const float* ad1 = (const float*)d_in[4];
    const float* b1  = (const float*)d_in[5];
    const float* W2  = (const float*)d_in[6];
    const float* as2 = (const float*)d_in[7];
    const float* ad2 = (const float*)d_in[8];
    const float* b2  = (const float*)d_in[9];
    float* out = (float*)d_out;

    char* ws = (char*)d_ws;
    size_t off = 0;
    auto alloc = [&](size_t bytes) -> void* {
        void* p = ws + off;
        off += (bytes + 255) & ~(size_t)255;
        return p;
    };
    unsigned short* h1h = (unsigned short*)alloc((size_t)N_NODES * 128 * 2);
    float* out1  = (float*)alloc((size_t)N_NODES * 128 * 4);
    float* als1v = (float*)alloc((size_t)N_NODES * 4 * 4);
    float* ald1v = (float*)alloc((size_t)N_NODES * 4 * 4);
    unsigned short* h2h = (unsigned short*)alloc((size_t)N_NODES * 16 * 2);
    float* als2v = (float*)alloc((size_t)N_NODES * 4);
    float* ald2v = (float*)alloc((size_t)N_NODES * 4);
    int* rowptr  = (int*)alloc((size_t)N_NODES * 4);
    int* degv    = (int*)alloc((size_t)N_NODES * 4);
    int* gcur    = (int*)alloc((size_t)NBKT * 4);
    int* packed  = (int*)alloc((size_t)NBKT * CAP * 4);
    int* colA    = (int*)alloc((size_t)NBKT * CAP * 4);

    hipMemsetAsync(gcur, 0, (size_t)NBKT * 4, stream);
    k_part_gemm1<<<PART_B + GEMM1_B, 256, 0, stream>>>(ei, gcur, packed,
                                                       x, W1, as1, ad1, h1h, als1v, ald1v);
    k_build<<<NBKT, 512, 0, stream>>>(packed, gcur, rowptr, degv, colA);
    k_agg1<<<N_NODES / 4, 256, 0, stream>>>(h1h, als1v, ald1v, rowptr, degv, colA, b1, out1);
    k_gemm2<<<N_NODES / 16, 256, 0, stream>>>(out1, W2, as2, ad2, h2h, als2v, ald2v);
    k_agg2<<<N_NODES / 4, 256, 0, stream>>>(h2h, als2v, ald2v, rowptr, degv, colA, b2, out);
}